// Round 9
// baseline (922.016 us; speedup 1.0000x reference)
//
#include <hip/hip_runtime.h>
#include <stdint.h>

#define TD 512
#define TH 2048
#define TE 8
#define TT 16384

typedef __bf16 bf16x8 __attribute__((ext_vector_type(8)));
typedef __bf16 bf16x4 __attribute__((ext_vector_type(4)));
typedef float  f32x4  __attribute__((ext_vector_type(4)));

__device__ __forceinline__ void async16(const void* src, void* lds) {
    __builtin_amdgcn_global_load_lds((const __attribute__((address_space(1))) uint32_t*)src,
                                     (__attribute__((address_space(3))) uint32_t*)lds,
                                     16, 0, 0);
}

// ---------------------------------------------------------------------------
// Gate: per-token LayerNorm -> logits -> softmax -> gate_w; cast x->bf16;
// write out_bias[t][d] = sum_e gw[t][e]*b2[e][d] directly into d_out.
// ---------------------------------------------------------------------------
__global__ __launch_bounds__(256) void gate_kernel(
    const float* __restrict__ x, const float* __restrict__ gamma,
    const float* __restrict__ beta, const float* __restrict__ gW,
    const float* __restrict__ gb, const float* __restrict__ b2,
    float* __restrict__ gate_w, __bf16* __restrict__ xb,
    float* __restrict__ outp)
{
    const int t    = blockIdx.x * 4 + (threadIdx.x >> 6);
    const int lane = threadIdx.x & 63;

    const float* xr = x + (size_t)t * TD + lane * 8;
    float4 v0 = *(const float4*)xr;
    float4 v1 = *(const float4*)(xr + 4);
    float xv[8] = {v0.x, v0.y, v0.z, v0.w, v1.x, v1.y, v1.z, v1.w};

    float s = 0.f, sq = 0.f;
    #pragma unroll
    for (int j = 0; j < 8; ++j) { s += xv[j]; sq += xv[j] * xv[j]; }
    #pragma unroll
    for (int off = 32; off > 0; off >>= 1) {
        s  += __shfl_xor(s, off);
        sq += __shfl_xor(sq, off);
    }
    const float mean = s * (1.f / TD);
    const float var  = sq * (1.f / TD) - mean * mean;
    const float rs   = rsqrtf(var + 1e-5f);

    bf16x8 xc;
    #pragma unroll
    for (int j = 0; j < 8; ++j) xc[j] = (__bf16)xv[j];
    *(bf16x8*)&xb[(size_t)t * TD + lane * 8] = xc;

    float p[TE] = {};
    #pragma unroll
    for (int j = 0; j < 8; ++j) {
        const int d = lane * 8 + j;
        const float xn = (xv[j] - mean) * rs * gamma[d] + beta[d];
        const float* wr = gW + (size_t)d * TE;
        #pragma unroll
        for (int e = 0; e < TE; ++e) p[e] += xn * wr[e];
    }
    #pragma unroll
    for (int off = 32; off > 0; off >>= 1) {
        #pragma unroll
        for (int e = 0; e < TE; ++e) p[e] += __shfl_xor(p[e], off);
    }

    float m = -3.4e38f;
    #pragma unroll
    for (int e = 0; e < TE; ++e) { p[e] += gb[e]; m = fmaxf(m, p[e]); }
    float sum = 0.f;
    #pragma unroll
    for (int e = 0; e < TE; ++e) { p[e] = expf(p[e] - m); sum += p[e]; }
    const float inv = 1.f / sum;
    if (lane == 0) {
        #pragma unroll
        for (int e = 0; e < TE; ++e) gate_w[(size_t)t * TE + e] = p[e] * inv;
    }

    float ob[8] = {};
    #pragma unroll
    for (int e = 0; e < TE; ++e) {
        const float we = p[e] * inv;
        const float* b2r = b2 + (size_t)e * TD + lane * 8;
        #pragma unroll
        for (int j = 0; j < 8; ++j) ob[j] += we * b2r[j];
    }
    float4 o0 = {ob[0], ob[1], ob[2], ob[3]};
    float4 o1 = {ob[4], ob[5], ob[6], ob[7]};
    *(float4*)&outp[(size_t)t * TD + lane * 8]     = o0;
    *(float4*)&outp[(size_t)t * TD + lane * 8 + 4] = o1;
}

// ---------------------------------------------------------------------------
// Transpose-cast.  src f32 [E][R][C].
// MODE 0 (W1): dst[e][c][r]                      (row stride R)
// MODE 1 (W2): dst[e>>1][c][(e&1)*R + r]         (row stride 2R = 4096)
// ---------------------------------------------------------------------------
template <int MODE>
__global__ __launch_bounds__(256) void tcast(
    const float* __restrict__ src, __bf16* __restrict__ dst, int R, int C)
{
    __shared__ __bf16 tile[64][65];
    const int e  = blockIdx.z;
    const int r0 = blockIdx.y * 64, c0 = blockIdx.x * 64;
    const int tr = threadIdx.x >> 6;
    const int tc = threadIdx.x & 63;

    const float* s = src + ((size_t)e * R + r0) * C + c0;
    #pragma unroll
    for (int i = 0; i < 16; ++i) {
        const int r = i * 4 + tr;
        tile[r][tc] = (__bf16)s[(size_t)r * C + tc];
    }
    __syncthreads();

    size_t RS, eoff;
    if (MODE == 0) { RS = (size_t)R;     eoff = (size_t)e * C * R; }
    else           { RS = (size_t)2 * R; eoff = (size_t)(e >> 1) * C * 2 * R + (size_t)(e & 1) * R; }

    __bf16* d = dst + eoff + (size_t)c0 * RS + r0;
    #pragma unroll
    for (int i = 0; i < 16; ++i) {
        const int c = i * 4 + tr;
        d[(size_t)c * RS + tc] = tile[tc][c];
    }
}

// ---------------------------------------------------------------------------
// m97-structure bf16 MFMA GEMM: 128x128 tile, BK=32, 4 waves (2x2, 64x64
// each, acc[4][4]), SINGLE-buffered 16 KiB LDS, plain 2-syncthreads loop
// (stage -> sync -> 8 ds_read_b128 + 16 MFMA -> sync), no inline asm.
// __launch_bounds__(256,4) -> 4 blocks/CU: independent-block overlap
// (m114/m103) hides the per-iter barrier drain.
// Stage dest is LANE-LINEAR (cid*16, rule 21/m104: global_load_lds writes
// wave-uniform base + lane*16 only) with inverse-XOR-swizzled global source;
// ds_read applies the same XOR: chunk c' = c ^ ((row>>1)&3). 0-conflict
// (measured r2-r7).
//
// EPI 0 (GEMM1): A=xb [T][512], Bt=W1t, K=512 (NT=16), 2 experts/launch.
//   Grid 4096 = bm(128, inner) x bn(16) x e2(2).
//   SWAPPED MFMA operands -> lane&15 = M-row, (lane>>4)*4+j = N-col ->
//   packed 8B bf16x4 stores h[row][e2*TH+col] (row stride 2*TH).
//   h' = bf16(gw[row][e] * leaky(acc + b1[col])).
// EPI 1 (GEMM2): A=h [T][4096], Bt=W2tc, K-half 2048 (NT=64).
//   Grid 1024 = bm(128, inner) x bn(4) x kh(2); atomicAdd f32 into d_out
//   (gate-weighted b2 prefilled by gate_kernel).
// ---------------------------------------------------------------------------
template <int EPI>
__global__ __launch_bounds__(256, 4) void gemm_sb(
    const __bf16* __restrict__ A, const __bf16* __restrict__ Bt,
    const float* __restrict__ b1, const float* __restrict__ gw,
    void* __restrict__ C, int grp)
{
    constexpr int S  = (EPI == 0) ? TD : 2 * TH;   // global row stride
    constexpr int NT = (EPI == 0) ? 16 : 64;       // K-tiles of 32 per block

    __shared__ __align__(16) char smem[16384];     // A [128][32] | B [128][32]

    const int tid  = threadIdx.x;
    const int w    = tid >> 6, lane = tid & 63;
    const int wr   = w >> 1, wc = w & 1;           // 2x2 waves, 64x64 each
    const int fr   = lane & 15, ks = lane >> 4;

    int bm, bn, e2 = 0, e = 0;
    if (EPI == 0) {
        bm = blockIdx.x & 127;                     // inner
        const int r = blockIdx.x >> 7;             // 0..31
        bn = r & 15;
        e2 = r >> 4;
        e  = grp * 2 + e2;
        A  += (size_t)bm * 128 * S;
        Bt += (size_t)e2 * TH * TD + (size_t)bn * 128 * S;
        b1 += (size_t)e * TH;
    } else {
        bm = blockIdx.x & 127;
        const int r = blockIdx.x >> 7;             // 0..7
        bn = r & 3;
        const int kh = r >> 2;                     // K-half of 2048
        A  += (size_t)bm * 128 * S + (size_t)kh * 2048;
        Bt += (size_t)bn * 128 * S + (size_t)kh * 2048;
    }

    const __bf16* Ab = A;
    const __bf16* Bb = Bt;

    f32x4 acc[4][4] = {};

    for (int t = 0; t < NT; ++t) {
        // ---- stage K-tile t: A 8KB + B 8KB, lane-linear dest (cid*16) ----
        #pragma unroll
        for (int p = 0; p < 2; ++p) {
            const int cid = p * 256 + tid;
            const int row = cid >> 2;              // 0..127
            const int gc  = (cid & 3) ^ ((row >> 1) & 3);
            async16(Ab + (size_t)row * S + t * 32 + gc * 8, smem + cid * 16);
        }
        #pragma unroll
        for (int p = 0; p < 2; ++p) {
            const int cid = p * 256 + tid;
            const int row = cid >> 2;
            const int gc  = (cid & 3) ^ ((row >> 1) & 3);
            async16(Bb + (size_t)row * S + t * 32 + gc * 8, smem + 8192 + cid * 16);
        }
        __syncthreads();                            // drains vmcnt; tile visible

        bf16x8 areg[4], breg[4];
        #pragma unroll
        for (int m = 0; m < 4; ++m) {
            const int row = wr * 64 + m * 16 + fr;
            areg[m] = *(const bf16x8*)(smem + row * 64 + (((ks ^ (row >> 1)) & 3) << 4));
        }
        #pragma unroll
        for (int n = 0; n < 4; ++n) {
            const int row = wc * 64 + n * 16 + fr;
            breg[n] = *(const bf16x8*)(smem + 8192 + row * 64 + (((ks ^ (row >> 1)) & 3) << 4));
        }
        #pragma unroll
        for (int m = 0; m < 4; ++m)
            #pragma unroll
            for (int n = 0; n < 4; ++n) {
                if (EPI == 0)   // swapped: lane&15 -> M-row, reg j -> N-col
                    acc[m][n] = __builtin_amdgcn_mfma_f32_16x16x32_bf16(breg[n], areg[m], acc[m][n], 0, 0, 0);
                else
                    acc[m][n] = __builtin_amdgcn_mfma_f32_16x16x32_bf16(areg[m], breg[n], acc[m][n], 0, 0, 0);
            }
        __syncthreads();                            // reads consumed before overwrite
    }

    if (EPI == 0) {
        // swapped: lane&15 = row, (lane>>4)*4 + j = col
        __bf16* hC = (__bf16*)C;
        const int rjc = (lane >> 4) << 2;
        #pragma unroll
        for (int m = 0; m < 4; ++m) {
            const int row = bm * 128 + wr * 64 + m * 16 + fr;
            const float wgt = gw[(size_t)row * TE + e];
            __bf16* hrow = hC + (size_t)row * (2 * TH) + e2 * TH;
            #pragma unroll
            for (int n = 0; n < 4; ++n) {
                const int colb = bn * 128 + wc * 64 + n * 16 + rjc;
                const f32x4 bv = *(const f32x4*)&b1[colb];
                bf16x4 ov;
                #pragma unroll
                for (int j = 0; j < 4; ++j) {
                    float v = acc[m][n][j] + bv[j];
                    v = v > 0.f ? v : 0.01f * v;
                    ov[j] = (__bf16)(v * wgt);
                }
                *(bf16x4*)&hrow[colb] = ov;
            }
        }
    } else {
        // normal: col = lane&15, row = (lane>>4)*4 + j
        float* oC = (float*)C;
        const int rj = (lane >> 4) << 2;
        #pragma unroll
        for (int m = 0; m < 4; ++m) {
            const int gr0 = bm * 128 + wr * 64 + m * 16 + rj;
            #pragma unroll
            for (int j = 0; j < 4; ++j) {
                const int gr = gr0 + j;
                #pragma unroll
                for (int n = 0; n < 4; ++n) {
                    const int gc = bn * 128 + wc * 64 + n * 16 + fr;
                    atomicAdd(oC + (size_t)gr * TD + gc, acc[m][n][j]);
                }
            }
        }
    }
}

// ---------------------------------------------------------------------------
extern "C" void kernel_launch(void* const* d_in, const int* in_sizes, int n_in,
                              void* d_out, int out_size, void* d_ws, size_t ws_size,
                              hipStream_t stream)
{
    const float* x     = (const float*)d_in[0];
    const float* gamma = (const float*)d_in[1];
    const float* beta  = (const float*)d_in[2];
    const float* gW    = (const float*)d_in[3];
    const float* gb    = (const float*)d_in[4];
    const float* W1    = (const float*)d_in[5];
    const float* b1    = (const float*)d_in[6];
    const float* W2    = (const float*)d_in[7];
    const float* b2    = (const float*)d_in[8];

    char* ws = (char*)d_ws;
    size_t off = 0;
    float*  gate_w = (float*)(ws + off);  off += (size_t)TT * TE * 4;        // 0.5 MB
    __bf16* xb     = (__bf16*)(ws + off); off += (size_t)TT * TD * 2;        // 16 MB
    __bf16* W1t    = (__bf16*)(ws + off); off += (size_t)TE * TD * TH * 2;   // 16 MB
    __bf16* W2tc   = (__bf16*)(ws + off); off += (size_t)TE * TD * TH * 2;   // 16 MB
    __bf16* h      = (__bf16*)(ws + off);                                    // 128 MB

    gate_kernel<<<TT / 4, 256, 0, stream>>>(x, gamma, beta, gW, gb, b2,
                                            gate_w, xb, (float*)d_out);
    // W1 [E][D][H] -> W1t [E][H][D]
    tcast<0><<<dim3(TH / 64, TD / 64, TE), 256, 0, stream>>>(W1, W1t, TD, TH);
    // W2 [E][H][D] -> W2tc [E/2][D][2*TH] (pair-concat along K)
    tcast<1><<<dim3(TD / 64, TH / 64, TE), 256, 0, stream>>>(W2, W2tc, TH, TD);

    for (int grp = 0; grp < 4; ++grp) {
        gemm_sb<0><<<4096, 256, 0, stream>>>(
            xb, W1t + (size_t)grp * 2 * TH * TD, b1, gate_w, (void*)h, grp);
        gemm_sb<1><<<1024, 256, 0, stream>>>(
            h, W2tc + (size_t)grp * TD * 2 * TH, nullptr, nullptr, d_out, grp);
    }
}

// Round 10
// 848.665 us; speedup vs baseline: 1.0864x; 1.0864x over previous
//
#include <hip/hip_runtime.h>
#include <stdint.h>

#define TD 512
#define TH 2048
#define TE 8
#define TT 16384

typedef __bf16 bf16x8 __attribute__((ext_vector_type(8)));
typedef __bf16 bf16x4 __attribute__((ext_vector_type(4)));
typedef float  f32x4  __attribute__((ext_vector_type(4)));

__device__ __forceinline__ void async16(const void* src, void* lds) {
    __builtin_amdgcn_global_load_lds((const __attribute__((address_space(1))) uint32_t*)src,
                                     (__attribute__((address_space(3))) uint32_t*)lds,
                                     16, 0, 0);
}

// ---------------------------------------------------------------------------
// Gate: per-token LayerNorm -> logits -> softmax -> gate_w; cast x->bf16;
// write out_bias[t][d] = sum_e gw[t][e]*b2[e][d] directly into d_out.
// ---------------------------------------------------------------------------
__global__ __launch_bounds__(256) void gate_kernel(
    const float* __restrict__ x, const float* __restrict__ gamma,
    const float* __restrict__ beta, const float* __restrict__ gW,
    const float* __restrict__ gb, const float* __restrict__ b2,
    float* __restrict__ gate_w, __bf16* __restrict__ xb,
    float* __restrict__ outp)
{
    const int t    = blockIdx.x * 4 + (threadIdx.x >> 6);
    const int lane = threadIdx.x & 63;

    const float* xr = x + (size_t)t * TD + lane * 8;
    float4 v0 = *(const float4*)xr;
    float4 v1 = *(const float4*)(xr + 4);
    float xv[8] = {v0.x, v0.y, v0.z, v0.w, v1.x, v1.y, v1.z, v1.w};

    float s = 0.f, sq = 0.f;
    #pragma unroll
    for (int j = 0; j < 8; ++j) { s += xv[j]; sq += xv[j] * xv[j]; }
    #pragma unroll
    for (int off = 32; off > 0; off >>= 1) {
        s  += __shfl_xor(s, off);
        sq += __shfl_xor(sq, off);
    }
    const float mean = s * (1.f / TD);
    const float var  = sq * (1.f / TD) - mean * mean;
    const float rs   = rsqrtf(var + 1e-5f);

    bf16x8 xc;
    #pragma unroll
    for (int j = 0; j < 8; ++j) xc[j] = (__bf16)xv[j];
    *(bf16x8*)&xb[(size_t)t * TD + lane * 8] = xc;

    float p[TE] = {};
    #pragma unroll
    for (int j = 0; j < 8; ++j) {
        const int d = lane * 8 + j;
        const float xn = (xv[j] - mean) * rs * gamma[d] + beta[d];
        const float* wr = gW + (size_t)d * TE;
        #pragma unroll
        for (int e = 0; e < TE; ++e) p[e] += xn * wr[e];
    }
    #pragma unroll
    for (int off = 32; off > 0; off >>= 1) {
        #pragma unroll
        for (int e = 0; e < TE; ++e) p[e] += __shfl_xor(p[e], off);
    }

    float m = -3.4e38f;
    #pragma unroll
    for (int e = 0; e < TE; ++e) { p[e] += gb[e]; m = fmaxf(m, p[e]); }
    float sum = 0.f;
    #pragma unroll
    for (int e = 0; e < TE; ++e) { p[e] = expf(p[e] - m); sum += p[e]; }
    const float inv = 1.f / sum;
    if (lane == 0) {
        #pragma unroll
        for (int e = 0; e < TE; ++e) gate_w[(size_t)t * TE + e] = p[e] * inv;
    }

    float ob[8] = {};
    #pragma unroll
    for (int e = 0; e < TE; ++e) {
        const float we = p[e] * inv;
        const float* b2r = b2 + (size_t)e * TD + lane * 8;
        #pragma unroll
        for (int j = 0; j < 8; ++j) ob[j] += we * b2r[j];
    }
    float4 o0 = {ob[0], ob[1], ob[2], ob[3]};
    float4 o1 = {ob[4], ob[5], ob[6], ob[7]};
    *(float4*)&outp[(size_t)t * TD + lane * 8]     = o0;
    *(float4*)&outp[(size_t)t * TD + lane * 8 + 4] = o1;
}

// ---------------------------------------------------------------------------
// Transpose-cast.  src f32 [E][R][C].
// MODE 0 (W1): dst[e][c][r]                      (row stride R)
// MODE 1 (W2): dst[e>>1][c][(e&1)*R + r]         (row stride 2R = 4096)
// ---------------------------------------------------------------------------
template <int MODE>
__global__ __launch_bounds__(256) void tcast(
    const float* __restrict__ src, __bf16* __restrict__ dst, int R, int C)
{
    __shared__ __bf16 tile[64][65];
    const int e  = blockIdx.z;
    const int r0 = blockIdx.y * 64, c0 = blockIdx.x * 64;
    const int tr = threadIdx.x >> 6;
    const int tc = threadIdx.x & 63;

    const float* s = src + ((size_t)e * R + r0) * C + c0;
    #pragma unroll
    for (int i = 0; i < 16; ++i) {
        const int r = i * 4 + tr;
        tile[r][tc] = (__bf16)s[(size_t)r * C + tc];
    }
    __syncthreads();

    size_t RS, eoff;
    if (MODE == 0) { RS = (size_t)R;     eoff = (size_t)e * C * R; }
    else           { RS = (size_t)2 * R; eoff = (size_t)(e >> 1) * C * 2 * R + (size_t)(e & 1) * R; }

    __bf16* d = dst + eoff + (size_t)c0 * RS + r0;
    #pragma unroll
    for (int i = 0; i < 16; ++i) {
        const int c = i * 4 + tr;
        d[(size_t)c * RS + tc] = tile[tc][c];
    }
}

// ---------------------------------------------------------------------------
// GEMM1, M-persistent: r5's 128x256 dbuf machinery, but each block runs
// 4 M-subtiles serially -> 64 CONTINUOUS pipeline iterations (g = m4*16+kt).
// 4 waves (each 128M x 64N slice, swapped operands, acc[8][4]); 48 KiB LDS;
// grid 512 = bmg(32) x bn(8) x e2(2) = exactly 2 blocks/CU, one balanced
// pass; B-panel shared by 32 bmg-blocks (L2-hot).
// Per iter g: vmcnt(6) [tile g landed, g+1 in flight; vmcnt(0) at tail] ->
// barrier -> 12 ds_read_b128 -> lgkmcnt(0) -> barrier -> stage(g+2) ->
// setprio(1) 32 MFMA setprio(0) -> [if kt==15: epilogue for m4, acc reset].
// Epilogue stores enter the vmcnt queue AFTER stage(g+2); next iter's
// vmcnt(6) retires tiles g+1,g+2 + stores (over-sync only at M boundaries).
// Swizzle (proven 0-conflict): 16B chunk c' = c ^ ((row>>1)&3), both sides.
// Epilogue: h[row][e2*TH+col] = bf16(gw[row][e] * leaky(acc + b1[col])),
// packed 8B bf16x4 (row stride 2*TH).
// ---------------------------------------------------------------------------
__global__ __launch_bounds__(256, 2) void gemm1m(
    const __bf16* __restrict__ A, const __bf16* __restrict__ Bt,
    const float* __restrict__ b1, const float* __restrict__ gw,
    __bf16* __restrict__ hC, int grp)
{
    constexpr int S  = TD;      // 512
    constexpr int NG = 64;      // 4 M-subtiles x 16 kt, continuous

    __shared__ __align__(16) char smem[49152];   // A 2x8K | B 2x16K

    const int tid  = threadIdx.x;
    const int w    = tid >> 6, lane = tid & 63;
    const int fr   = lane & 15, ks = lane >> 4;

    const int bmg = blockIdx.x & 31;             // 32 groups of 4 M-tiles
    const int r   = blockIdx.x >> 5;             // 0..15
    const int bn  = r & 7;
    const int e2  = r >> 3;
    const int e   = grp * 2 + e2;

    const __bf16* Ab  = A  + (size_t)bmg * 512 * S;   // 4x128 rows
    const __bf16* Bb  = Bt + (size_t)e2 * TH * TD + (size_t)bn * 256 * S;
    const float*  b1e = b1 + (size_t)e * TH;

    f32x4 acc[8][4] = {};

    auto stage = [&](int g, int b) {
        const int m4 = g >> 4, kt = g & 15;
        char* aRegion = smem + b * 8192;
        char* bRegion = smem + 16384 + b * 16384;
        const __bf16* Am = Ab + (size_t)m4 * 128 * S;
        #pragma unroll
        for (int p = 0; p < 2; ++p) {
            const int cid = p * 256 + tid;
            const int row = cid >> 2;            // 0..127
            const int gc  = (cid & 3) ^ ((row >> 1) & 3);
            async16(Am + (size_t)row * S + kt * 32 + gc * 8, aRegion + cid * 16);
        }
        #pragma unroll
        for (int p = 0; p < 4; ++p) {
            const int cid = p * 256 + tid;
            const int row = cid >> 2;            // 0..255
            const int gc  = (cid & 3) ^ ((row >> 1) & 3);
            async16(Bb + (size_t)row * S + kt * 32 + gc * 8, bRegion + cid * 16);
        }
    };

    stage(0, 0);
    stage(1, 1);

    for (int g = 0; g < NG; ++g) {
        const int buf = g & 1;
        const char* aR = smem + buf * 8192;
        const char* bR = smem + 16384 + buf * 16384;

        if (g + 1 < NG) { asm volatile("s_waitcnt vmcnt(6)" ::: "memory"); }
        else            { asm volatile("s_waitcnt vmcnt(0)" ::: "memory"); }
        __builtin_amdgcn_sched_barrier(0);
        __builtin_amdgcn_s_barrier();

        bf16x8 areg[8], breg[4];
        #pragma unroll
        for (int m = 0; m < 8; ++m) {
            const int row = m * 16 + fr;
            areg[m] = *(const bf16x8*)(aR + row * 64 + (((ks ^ (row >> 1)) & 3) << 4));
        }
        #pragma unroll
        for (int n = 0; n < 4; ++n) {
            const int row = w * 64 + n * 16 + fr;
            breg[n] = *(const bf16x8*)(bR + row * 64 + (((ks ^ (row >> 1)) & 3) << 4));
        }
        asm volatile("s_waitcnt lgkmcnt(0)" ::: "memory");
        __builtin_amdgcn_sched_barrier(0);
        __builtin_amdgcn_s_barrier();            // all waves' reads done

        if (g + 2 < NG) stage(g + 2, buf);       // overwrite just-read buf

        __builtin_amdgcn_s_setprio(1);
        #pragma unroll
        for (int m = 0; m < 8; ++m)
            #pragma unroll
            for (int n = 0; n < 4; ++n)          // swapped: lane&15 -> M-row
                acc[m][n] = __builtin_amdgcn_mfma_f32_16x16x32_bf16(breg[n], areg[m], acc[m][n], 0, 0, 0);
        __builtin_amdgcn_s_setprio(0);
        __builtin_amdgcn_sched_barrier(0);

        if ((g & 15) == 15) {                    // M-subtile epilogue
            const int m4  = g >> 4;
            const int rjc = (lane >> 4) << 2;
            #pragma unroll
            for (int m = 0; m < 8; ++m) {
                const int row = (bmg * 4 + m4) * 128 + m * 16 + fr;
                const float wgt = gw[(size_t)row * TE + e];
                __bf16* hrow = hC + (size_t)row * (2 * TH) + e2 * TH;
                #pragma unroll
                for (int n = 0; n < 4; ++n) {
                    const int colb = bn * 256 + w * 64 + n * 16 + rjc;
                    const f32x4 bv = *(const f32x4*)&b1e[colb];
                    bf16x4 ov;
                    #pragma unroll
                    for (int j = 0; j < 4; ++j) {
                        float v = acc[m][n][j] + bv[j];
                        v = v > 0.f ? v : 0.01f * v;
                        ov[j] = (__bf16)(v * wgt);
                        acc[m][n][j] = 0.f;
                    }
                    *(bf16x4*)&hrow[colb] = ov;
                }
            }
        }
    }
}

// ---------------------------------------------------------------------------
// GEMM2 (r5-proven, unchanged): 128x256 tile, BK=32, 4 waves (w owns 64-col
// N-slice), 48 KiB LDS dbuf, NT=64 (K-half 2048), grid 512 = 2/CU balanced.
// A=h [T][4096], Bt=W2tc panel; atomicAdd f32 into d_out.
// ---------------------------------------------------------------------------
__global__ __launch_bounds__(256, 2) void gemm2k(
    const __bf16* __restrict__ A, const __bf16* __restrict__ Bt,
    float* __restrict__ oC)
{
    constexpr int S  = 2 * TH;                   // 4096
    constexpr int NT = 64;

    __shared__ __align__(16) char smem[49152];

    const int tid  = threadIdx.x;
    const int w    = tid >> 6, lane = tid & 63;
    const int fr   = lane & 15, ks = lane >> 4;

    const int xcd = blockIdx.x & 7, idx = blockIdx.x >> 3;  // 8 x 64
    const int bm  = xcd * 16 + (idx & 15);       // 0..127
    const int pn  = idx >> 4;                    // 0..3
    const int kh  = pn >> 1;                     // k-half: 2048 elements
    const int bn  = pn & 1;

    const __bf16* Ab = A  + (size_t)bm * 128 * S + (size_t)kh * 2048;
    const __bf16* Bb = Bt + (size_t)bn * 256 * S + (size_t)kh * 2048;

    f32x4 acc[8][4] = {};

    auto stage = [&](int t, int b) {
        char* aRegion = smem + b * 8192;
        char* bRegion = smem + 16384 + b * 16384;
        #pragma unroll
        for (int p = 0; p < 2; ++p) {
            const int cid = p * 256 + tid;
            const int row = cid >> 2;
            const int gc  = (cid & 3) ^ ((row >> 1) & 3);
            async16(Ab + (size_t)row * S + t * 32 + gc * 8, aRegion + cid * 16);
        }
        #pragma unroll
        for (int p = 0; p < 4; ++p) {
            const int cid = p * 256 + tid;
            const int row = cid >> 2;
            const int gc  = (cid & 3) ^ ((row >> 1) & 3);
            async16(Bb + (size_t)row * S + t * 32 + gc * 8, bRegion + cid * 16);
        }
    };

    stage(0, 0);
    stage(1, 1);

    for (int t = 0; t < NT; ++t) {
        const int buf = t & 1;
        const char* aR = smem + buf * 8192;
        const char* bR = smem + 16384 + buf * 16384;

        if (t + 1 < NT) { asm volatile("s_waitcnt vmcnt(6)" ::: "memory"); }
        else            { asm volatile("s_waitcnt vmcnt(0)" ::: "memory"); }
        __builtin_amdgcn_sched_barrier(0);
        __builtin_amdgcn_s_barrier();

        bf16x8 areg[8], breg[4];
        #pragma unroll
        for (int m = 0; m < 8; ++m) {
            const int row = m * 16 + fr;
            areg[m] = *(const bf16x8*)(aR + row * 64 + (((ks ^ (row >> 1)) & 3) << 4));
        }
        #pragma unroll
        for (int n = 0; n < 4; ++n) {
            const int row = w * 64 + n * 16 + fr;
            breg[n] = *(const bf16x8*)(bR + row * 64 + (((ks ^ (row >> 1)) & 3) << 4));
        }
        asm volatile("s_waitcnt lgkmcnt(0)" ::: "memory");
        __builtin_amdgcn_sched_barrier(0);
        __builtin_amdgcn_s_barrier();            // all waves' reads done

        if (t + 2 < NT) stage(t + 2, buf);

        __builtin_amdgcn_s_setprio(1);
        #pragma unroll
        for (int m = 0; m < 8; ++m)
            #pragma unroll
            for (int n = 0; n < 4; ++n)
                acc[m][n] = __builtin_amdgcn_mfma_f32_16x16x32_bf16(areg[m], breg[n], acc[m][n], 0, 0, 0);
        __builtin_amdgcn_s_setprio(0);
        __builtin_amdgcn_sched_barrier(0);
    }

    // normal C/D map: col = lane&15, row = (lane>>4)*4 + j
    const int rj = (lane >> 4) << 2;
    #pragma unroll
    for (int m = 0; m < 8; ++m) {
        const int gr0 = bm * 128 + m * 16 + rj;
        #pragma unroll
        for (int j = 0; j < 4; ++j) {
            const int gr = gr0 + j;
            #pragma unroll
            for (int n = 0; n < 4; ++n) {
                const int gc = bn * 256 + w * 64 + n * 16 + fr;
                atomicAdd(oC + (size_t)gr * TD + gc, acc[m][n][j]);
            }
        }
    }
}

// ---------------------------------------------------------------------------
extern "C" void kernel_launch(void* const* d_in, const int* in_sizes, int n_in,
                              void* d_out, int out_size, void* d_ws, size_t ws_size,
                              hipStream_t stream)
{
    const float* x     = (const float*)d_in[0];
    const float* gamma = (const float*)d_in[1];
    const float* beta  = (const float*)d_in[2];
    const float* gW    = (const float*)d_in[3];
    const float* gb    = (const float*)d_in[4];
    const float* W1    = (const float*)d_in[5];
    const float* b1    = (const float*)d_in[6];
    const float* W2    = (const float*)d_in[7];
    const float* b2    = (const float*)d_in[8];

    char* ws = (char*)d_ws;
    size_t off = 0;
    float*  gate_w = (float*)(ws + off);  off += (size_t)TT * TE * 4;        // 0.5 MB
    __bf16* xb     = (__bf16*)(ws + off); off += (size_t)TT * TD * 2;        // 16 MB
    __bf16* W1t    = (__bf16*)(ws + off); off += (size_t)TE * TD * TH * 2;   // 16 MB
    __bf16* W2tc   = (__bf16*)(ws + off); off += (size_t)TE * TD * TH * 2;   // 16 MB
    __bf16* h      = (__bf16*)(ws + off);                                    // 128 MB

    gate_kernel<<<TT / 4, 256, 0, stream>>>(x, gamma, beta, gW, gb, b2,
                                            gate_w, xb, (float*)d_out);
    // W1 [E][D][H] -> W1t [E][H][D]
    tcast<0><<<dim3(TH / 64, TD / 64, TE), 256, 0, stream>>>(W1, W1t, TD, TH);
    // W2 [E][H][D] -> W2tc [E/2][D][2*TH] (pair-concat along K)
    tcast<1><<<dim3(TD / 64, TH / 64, TE), 256, 0, stream>>>(W2, W2tc, TH, TD);

    for (int grp = 0; grp < 4; ++grp) {
        gemm1m<<<512, 256, 0, stream>>>(
            xb, W1t + (size_t)grp * 2 * TH * TD, b1, gate_w, h, grp);
        gemm2k<<<512, 256, 0, stream>>>(
            h, W2tc + (size_t)grp * TD * 2 * TH, (float*)d_out);
    }
}

// Round 11
// 774.441 us; speedup vs baseline: 1.1906x; 1.0958x over previous
//
#include <hip/hip_runtime.h>
#include <stdint.h>

#define TD 512
#define TH 2048
#define TE 8
#define TT 16384

typedef __bf16 bf16x8 __attribute__((ext_vector_type(8)));
typedef __bf16 bf16x4 __attribute__((ext_vector_type(4)));
typedef float  f32x4  __attribute__((ext_vector_type(4)));

__device__ __forceinline__ void async16(const void* src, void* lds) {
    __builtin_amdgcn_global_load_lds((const __attribute__((address_space(1))) uint32_t*)src,
                                     (__attribute__((address_space(3))) uint32_t*)lds,
                                     16, 0, 0);
}

// ---------------------------------------------------------------------------
// Gate: per-token LayerNorm -> logits -> softmax -> gate_w; cast x->bf16;
// write out_bias[t][d] = sum_e gw[t][e]*b2[e][d] directly into d_out.
// ---------------------------------------------------------------------------
__global__ __launch_bounds__(256) void gate_kernel(
    const float* __restrict__ x, const float* __restrict__ gamma,
    const float* __restrict__ beta, const float* __restrict__ gW,
    const float* __restrict__ gb, const float* __restrict__ b2,
    float* __restrict__ gate_w, __bf16* __restrict__ xb,
    float* __restrict__ outp)
{
    const int t    = blockIdx.x * 4 + (threadIdx.x >> 6);
    const int lane = threadIdx.x & 63;

    const float* xr = x + (size_t)t * TD + lane * 8;
    float4 v0 = *(const float4*)xr;
    float4 v1 = *(const float4*)(xr + 4);
    float xv[8] = {v0.x, v0.y, v0.z, v0.w, v1.x, v1.y, v1.z, v1.w};

    float s = 0.f, sq = 0.f;
    #pragma unroll
    for (int j = 0; j < 8; ++j) { s += xv[j]; sq += xv[j] * xv[j]; }
    #pragma unroll
    for (int off = 32; off > 0; off >>= 1) {
        s  += __shfl_xor(s, off);
        sq += __shfl_xor(sq, off);
    }
    const float mean = s * (1.f / TD);
    const float var  = sq * (1.f / TD) - mean * mean;
    const float rs   = rsqrtf(var + 1e-5f);

    bf16x8 xc;
    #pragma unroll
    for (int j = 0; j < 8; ++j) xc[j] = (__bf16)xv[j];
    *(bf16x8*)&xb[(size_t)t * TD + lane * 8] = xc;

    float p[TE] = {};
    #pragma unroll
    for (int j = 0; j < 8; ++j) {
        const int d = lane * 8 + j;
        const float xn = (xv[j] - mean) * rs * gamma[d] + beta[d];
        const float* wr = gW + (size_t)d * TE;
        #pragma unroll
        for (int e = 0; e < TE; ++e) p[e] += xn * wr[e];
    }
    #pragma unroll
    for (int off = 32; off > 0; off >>= 1) {
        #pragma unroll
        for (int e = 0; e < TE; ++e) p[e] += __shfl_xor(p[e], off);
    }

    float m = -3.4e38f;
    #pragma unroll
    for (int e = 0; e < TE; ++e) { p[e] += gb[e]; m = fmaxf(m, p[e]); }
    float sum = 0.f;
    #pragma unroll
    for (int e = 0; e < TE; ++e) { p[e] = expf(p[e] - m); sum += p[e]; }
    const float inv = 1.f / sum;
    if (lane == 0) {
        #pragma unroll
        for (int e = 0; e < TE; ++e) gate_w[(size_t)t * TE + e] = p[e] * inv;
    }

    float ob[8] = {};
    #pragma unroll
    for (int e = 0; e < TE; ++e) {
        const float we = p[e] * inv;
        const float* b2r = b2 + (size_t)e * TD + lane * 8;
        #pragma unroll
        for (int j = 0; j < 8; ++j) ob[j] += we * b2r[j];
    }
    float4 o0 = {ob[0], ob[1], ob[2], ob[3]};
    float4 o1 = {ob[4], ob[5], ob[6], ob[7]};
    *(float4*)&outp[(size_t)t * TD + lane * 8]     = o0;
    *(float4*)&outp[(size_t)t * TD + lane * 8 + 4] = o1;
}

// ---------------------------------------------------------------------------
// Transpose-cast.  src f32 [E][R][C].
// MODE 0 (W1): dst[e][c][r]                      (row stride R)
// MODE 1 (W2): dst[e>>1][c][(e&1)*R + r]         (row stride 2R = 4096)
// ---------------------------------------------------------------------------
template <int MODE>
__global__ __launch_bounds__(256) void tcast(
    const float* __restrict__ src, __bf16* __restrict__ dst, int R, int C)
{
    __shared__ __bf16 tile[64][65];
    const int e  = blockIdx.z;
    const int r0 = blockIdx.y * 64, c0 = blockIdx.x * 64;
    const int tr = threadIdx.x >> 6;
    const int tc = threadIdx.x & 63;

    const float* s = src + ((size_t)e * R + r0) * C + c0;
    #pragma unroll
    for (int i = 0; i < 16; ++i) {
        const int r = i * 4 + tr;
        tile[r][tc] = (__bf16)s[(size_t)r * C + tc];
    }
    __syncthreads();

    size_t RS, eoff;
    if (MODE == 0) { RS = (size_t)R;     eoff = (size_t)e * C * R; }
    else           { RS = (size_t)2 * R; eoff = (size_t)(e >> 1) * C * 2 * R + (size_t)(e & 1) * R; }

    __bf16* d = dst + eoff + (size_t)c0 * RS + r0;
    #pragma unroll
    for (int i = 0; i < 16; ++i) {
        const int c = i * 4 + tr;
        d[(size_t)c * RS + tc] = tile[tc][c];
    }
}

// ---------------------------------------------------------------------------
// GEMM1, M-persistent (r10-proven, unchanged): 128x256 dbuf, 4 M-subtiles
// serially -> 64 continuous iters; grid 512 = bmg(32) x bn(8) x e2(2).
// ---------------------------------------------------------------------------
__global__ __launch_bounds__(256, 2) void gemm1m(
    const __bf16* __restrict__ A, const __bf16* __restrict__ Bt,
    const float* __restrict__ b1, const float* __restrict__ gw,
    __bf16* __restrict__ hC, int grp)
{
    constexpr int S  = TD;      // 512
    constexpr int NG = 64;      // 4 M-subtiles x 16 kt, continuous

    __shared__ __align__(16) char smem[49152];   // A 2x8K | B 2x16K

    const int tid  = threadIdx.x;
    const int w    = tid >> 6, lane = tid & 63;
    const int fr   = lane & 15, ks = lane >> 4;

    const int bmg = blockIdx.x & 31;             // 32 groups of 4 M-tiles
    const int r   = blockIdx.x >> 5;             // 0..15
    const int bn  = r & 7;
    const int e2  = r >> 3;
    const int e   = grp * 2 + e2;

    const __bf16* Ab  = A  + (size_t)bmg * 512 * S;   // 4x128 rows
    const __bf16* Bb  = Bt + (size_t)e2 * TH * TD + (size_t)bn * 256 * S;
    const float*  b1e = b1 + (size_t)e * TH;

    f32x4 acc[8][4] = {};

    auto stage = [&](int g, int b) {
        const int m4 = g >> 4, kt = g & 15;
        char* aRegion = smem + b * 8192;
        char* bRegion = smem + 16384 + b * 16384;
        const __bf16* Am = Ab + (size_t)m4 * 128 * S;
        #pragma unroll
        for (int p = 0; p < 2; ++p) {
            const int cid = p * 256 + tid;
            const int row = cid >> 2;            // 0..127
            const int gc  = (cid & 3) ^ ((row >> 1) & 3);
            async16(Am + (size_t)row * S + kt * 32 + gc * 8, aRegion + cid * 16);
        }
        #pragma unroll
        for (int p = 0; p < 4; ++p) {
            const int cid = p * 256 + tid;
            const int row = cid >> 2;            // 0..255
            const int gc  = (cid & 3) ^ ((row >> 1) & 3);
            async16(Bb + (size_t)row * S + kt * 32 + gc * 8, bRegion + cid * 16);
        }
    };

    stage(0, 0);
    stage(1, 1);

    for (int g = 0; g < NG; ++g) {
        const int buf = g & 1;
        const char* aR = smem + buf * 8192;
        const char* bR = smem + 16384 + buf * 16384;

        if (g + 1 < NG) { asm volatile("s_waitcnt vmcnt(6)" ::: "memory"); }
        else            { asm volatile("s_waitcnt vmcnt(0)" ::: "memory"); }
        __builtin_amdgcn_sched_barrier(0);
        __builtin_amdgcn_s_barrier();

        bf16x8 areg[8], breg[4];
        #pragma unroll
        for (int m = 0; m < 8; ++m) {
            const int row = m * 16 + fr;
            areg[m] = *(const bf16x8*)(aR + row * 64 + (((ks ^ (row >> 1)) & 3) << 4));
        }
        #pragma unroll
        for (int n = 0; n < 4; ++n) {
            const int row = w * 64 + n * 16 + fr;
            breg[n] = *(const bf16x8*)(bR + row * 64 + (((ks ^ (row >> 1)) & 3) << 4));
        }
        asm volatile("s_waitcnt lgkmcnt(0)" ::: "memory");
        __builtin_amdgcn_sched_barrier(0);
        __builtin_amdgcn_s_barrier();            // all waves' reads done

        if (g + 2 < NG) stage(g + 2, buf);       // overwrite just-read buf

        __builtin_amdgcn_s_setprio(1);
        #pragma unroll
        for (int m = 0; m < 8; ++m)
            #pragma unroll
            for (int n = 0; n < 4; ++n)          // swapped: lane&15 -> M-row
                acc[m][n] = __builtin_amdgcn_mfma_f32_16x16x32_bf16(breg[n], areg[m], acc[m][n], 0, 0, 0);
        __builtin_amdgcn_s_setprio(0);
        __builtin_amdgcn_sched_barrier(0);

        if ((g & 15) == 15) {                    // M-subtile epilogue
            const int m4  = g >> 4;
            const int rjc = (lane >> 4) << 2;
            #pragma unroll
            for (int m = 0; m < 8; ++m) {
                const int row = (bmg * 4 + m4) * 128 + m * 16 + fr;
                const float wgt = gw[(size_t)row * TE + e];
                __bf16* hrow = hC + (size_t)row * (2 * TH) + e2 * TH;
                #pragma unroll
                for (int n = 0; n < 4; ++n) {
                    const int colb = bn * 256 + w * 64 + n * 16 + rjc;
                    const f32x4 bv = *(const f32x4*)&b1e[colb];
                    bf16x4 ov;
                    #pragma unroll
                    for (int j = 0; j < 4; ++j) {
                        float v = acc[m][n][j] + bv[j];
                        v = v > 0.f ? v : 0.01f * v;
                        ov[j] = (__bf16)(v * wgt);
                        acc[m][n][j] = 0.f;
                    }
                    *(bf16x4*)&hrow[colb] = ov;
                }
            }
        }
    }
}

// ---------------------------------------------------------------------------
// GEMM2, atomic-free full-K: 128x128 tile, BK=32, FULL K=4096 (NT=128
// continuous), 4 waves (2x2, 64x64 each, acc[4][4]), 32 KiB LDS dbuf,
// vmcnt(4) counted lookahead, 4 blocks/CU (launch_bounds(256,4), ~60-100
// VGPR proven no-spill in r9). Grid 512 = bm(128, inner) x bn(4): exactly
// ONE writer per output tile -> plain read-add-store into d_out (prefilled
// with gate-weighted b2; grp launches serialize on stream).
// A=h [T][4096] (concat expert pair), Bt=W2tc [512][4096] rows.
// Swizzle (proven 0-conflict): 16B chunk c' = c ^ ((row>>1)&3), both sides.
// ---------------------------------------------------------------------------
__global__ __launch_bounds__(256, 4) void gemm2f(
    const __bf16* __restrict__ A, const __bf16* __restrict__ Bt,
    float* __restrict__ oC)
{
    constexpr int S  = 2 * TH;                   // 4096
    constexpr int NT = 128;                      // full K, 32 per tile

    __shared__ __align__(16) char smem[32768];   // A 2x8K | B 2x8K

    const int tid  = threadIdx.x;
    const int w    = tid >> 6, lane = tid & 63;
    const int wr   = w >> 1, wc = w & 1;         // 2x2 waves, 64x64 each
    const int fr   = lane & 15, ks = lane >> 4;

    const int bm = blockIdx.x & 127;             // inner: B-panel L2-hot
    const int bn = blockIdx.x >> 7;              // 0..3

    const __bf16* Ab = A  + (size_t)bm * 128 * S;
    const __bf16* Bb = Bt + (size_t)bn * 128 * S;

    f32x4 acc[4][4] = {};

    auto stage = [&](int t, int b) {
        char* aRegion = smem + b * 8192;
        char* bRegion = smem + 16384 + b * 8192;
        #pragma unroll
        for (int p = 0; p < 2; ++p) {
            const int cid = p * 256 + tid;
            const int row = cid >> 2;            // 0..127
            const int gc  = (cid & 3) ^ ((row >> 1) & 3);
            async16(Ab + (size_t)row * S + t * 32 + gc * 8, aRegion + cid * 16);
        }
        #pragma unroll
        for (int p = 0; p < 2; ++p) {
            const int cid = p * 256 + tid;
            const int row = cid >> 2;
            const int gc  = (cid & 3) ^ ((row >> 1) & 3);
            async16(Bb + (size_t)row * S + t * 32 + gc * 8, bRegion + cid * 16);
        }
    };

    stage(0, 0);
    stage(1, 1);

    for (int t = 0; t < NT; ++t) {
        const int buf = t & 1;
        const char* aR = smem + buf * 8192;
        const char* bR = smem + 16384 + buf * 8192;

        if (t + 1 < NT) { asm volatile("s_waitcnt vmcnt(4)" ::: "memory"); }
        else            { asm volatile("s_waitcnt vmcnt(0)" ::: "memory"); }
        __builtin_amdgcn_sched_barrier(0);
        __builtin_amdgcn_s_barrier();

        bf16x8 areg[4], breg[4];
        #pragma unroll
        for (int m = 0; m < 4; ++m) {
            const int row = wr * 64 + m * 16 + fr;
            areg[m] = *(const bf16x8*)(aR + row * 64 + (((ks ^ (row >> 1)) & 3) << 4));
        }
        #pragma unroll
        for (int n = 0; n < 4; ++n) {
            const int row = wc * 64 + n * 16 + fr;
            breg[n] = *(const bf16x8*)(bR + row * 64 + (((ks ^ (row >> 1)) & 3) << 4));
        }
        asm volatile("s_waitcnt lgkmcnt(0)" ::: "memory");
        __builtin_amdgcn_sched_barrier(0);
        __builtin_amdgcn_s_barrier();            // all waves' reads done

        if (t + 2 < NT) stage(t + 2, buf);       // overwrite just-read buf

        __builtin_amdgcn_s_setprio(1);
        #pragma unroll
        for (int m = 0; m < 4; ++m)
            #pragma unroll
            for (int n = 0; n < 4; ++n)
                acc[m][n] = __builtin_amdgcn_mfma_f32_16x16x32_bf16(areg[m], breg[n], acc[m][n], 0, 0, 0);
        __builtin_amdgcn_s_setprio(0);
        __builtin_amdgcn_sched_barrier(0);
    }

    // normal C/D map: col = lane&15, row = (lane>>4)*4 + j.
    // Single writer per tile per launch -> plain RMW (out prefilled).
    const int rj = (lane >> 4) << 2;
    #pragma unroll
    for (int m = 0; m < 4; ++m) {
        const int gr0 = bm * 128 + wr * 64 + m * 16 + rj;
        #pragma unroll
        for (int j = 0; j < 4; ++j) {
            const int gr = gr0 + j;
            #pragma unroll
            for (int n = 0; n < 4; ++n) {
                const int gc = bn * 128 + wc * 64 + n * 16 + fr;
                float* op = oC + (size_t)gr * TD + gc;
                *op += acc[m][n][j];
            }
        }
    }
}

// ---------------------------------------------------------------------------
extern "C" void kernel_launch(void* const* d_in, const int* in_sizes, int n_in,
                              void* d_out, int out_size, void* d_ws, size_t ws_size,
                              hipStream_t stream)
{
    const float* x     = (const float*)d_in[0];
    const float* gamma = (const float*)d_in[1];
    const float* beta  = (const float*)d_in[2];
    const float* gW    = (const float*)d_in[3];
    const float* gb    = (const float*)d_in[4];
    const float* W1    = (const float*)d_in[5];
    const float* b1    = (const float*)d_in[6];
    const float* W2    = (const float*)d_in[7];
    const float* b2    = (const float*)d_in[8];

    char* ws = (char*)d_ws;
    size_t off = 0;
    float*  gate_w = (float*)(ws + off);  off += (size_t)TT * TE * 4;        // 0.5 MB
    __bf16* xb     = (__bf16*)(ws + off); off += (size_t)TT * TD * 2;        // 16 MB
    __bf16* W1t    = (__bf16*)(ws + off); off += (size_t)TE * TD * TH * 2;   // 16 MB
    __bf16* W2tc   = (__bf16*)(ws + off); off += (size_t)TE * TD * TH * 2;   // 16 MB
    __bf16* h      = (__bf16*)(ws + off);                                    // 128 MB

    gate_kernel<<<TT / 4, 256, 0, stream>>>(x, gamma, beta, gW, gb, b2,
                                            gate_w, xb, (float*)d_out);
    // W1 [E][D][H] -> W1t [E][H][D]
    tcast<0><<<dim3(TH / 64, TD / 64, TE), 256, 0, stream>>>(W1, W1t, TD, TH);
    // W2 [E][H][D] -> W2tc [E/2][D][2*TH] (pair-concat along K)
    tcast<1><<<dim3(TD / 64, TH / 64, TE), 256, 0, stream>>>(W2, W2tc, TH, TD);

    for (int grp = 0; grp < 4; ++grp) {
        gemm1m<<<512, 256, 0, stream>>>(
            xb, W1t + (size_t)grp * 2 * TH * TD, b1, gate_w, h, grp);
        gemm2f<<<512, 256, 0, stream>>>(
            h, W2tc + (size_t)grp * TD * 2 * TH, (float*)d_out);
    }
}